// Round 13
// baseline (65.652 us; speedup 1.0000x reference)
//
#include <hip/hip_runtime.h>

#define NB 8
#define NC 256
#define NS 1024
#define NHEAD 4
#define HD 64
#define OC 768

// 0.125 (1/sqrt(HD)) * log2(e), folded into Q at qkv-write time
#define QSCALE 0.1803368801111204f

typedef float f32x4 __attribute__((ext_vector_type(4)));
typedef __bf16 bf16x8 __attribute__((ext_vector_type(8)));
typedef unsigned short u16;
typedef unsigned int u32;
typedef u16 u16x8 __attribute__((ext_vector_type(8)));
typedef u32 u32x2 __attribute__((ext_vector_type(2)));
typedef u32 u32x4 __attribute__((ext_vector_type(4)));
typedef int i32x4 __attribute__((ext_vector_type(4)));
typedef short s16x4 __attribute__((ext_vector_type(4)));

__device__ __forceinline__ u16 f2b(float f) {
    return __builtin_bit_cast(u16, (__bf16)f);  // hardware v_cvt (RNE)
}
__device__ __forceinline__ u32 pack2(float lo, float hi) {
    return (u32)f2b(lo) | ((u32)f2b(hi) << 16);  // fuses to v_cvt_pk_bf16_f32
}

__device__ __forceinline__ f32x4 MFMA(u16x8 a, u16x8 b, f32x4 c) {
    return __builtin_amdgcn_mfma_f32_16x16x32_bf16(
        __builtin_bit_cast(bf16x8, a), __builtin_bit_cast(bf16x8, b), c, 0, 0, 0);
}

// ------- kernel 1: BN-affine + transpose: in[b][c][s] f32 -> xt[b][s][c] bf16 -------
__global__ void xform(const float* __restrict__ in,
                      const float* __restrict__ gma, const float* __restrict__ bta,
                      const float* __restrict__ mu,  const float* __restrict__ var,
                      const float* __restrict__ dw,  u16* __restrict__ xt) {
    __shared__ float tile[32][33];
    __shared__ float ssc[32], ssh[32];
    int b = blockIdx.z, c0 = blockIdx.y * 32, s0 = blockIdx.x * 32;
    int tx = threadIdx.x & 31, ty = threadIdx.x >> 5;  // ty: 0..7
    if (threadIdx.x < 32) {
        int c = c0 + threadIdx.x;
        float sc = gma[c] * rsqrtf(var[c] + 1e-5f) * dw[c];
        ssc[threadIdx.x] = sc;
        ssh[threadIdx.x] = bta[c] * dw[c] - mu[c] * sc;
    }
    __syncthreads();
#pragma unroll
    for (int r = 0; r < 4; r++) {
        int c = ty + r * 8;
        tile[c][tx] = in[((size_t)b * NC + c0 + c) * NS + s0 + tx] * ssc[c] + ssh[c];
    }
    __syncthreads();
#pragma unroll
    for (int r = 0; r < 4; r++) {
        int s = ty + r * 8;
        xt[((size_t)b * NS + s0 + s) * NC + c0 + tx] = f2b(tile[tx][s]);
    }
}

// ---------------- kernel 2: QKV GEMM (768x1024x256 per batch) ----------------
// Tile 64x128, 4 waves (each 64x32), K-step 128 (2 iters, 4 barriers total).
// A staged from f32 pw inline. Global loads issued BEFORE the barrier.
// LDS 52.2KB/block -> still 3 blocks/CU (156.7 <= 160KB).
// Each 64-row m-tile is purely q, k, or v: sel=(m0/64)%3, block-uniform.
__global__ __launch_bounds__(256) void qkv_gemm(const float* __restrict__ pw, const u16* __restrict__ xt,
                                                u16* __restrict__ qb, u16* __restrict__ kb,
                                                u16* __restrict__ vb) {
    __shared__ __attribute__((aligned(16))) u16 Ws[64][136];
    __shared__ __attribute__((aligned(16))) u16 Xs[128][136];
    int b = blockIdx.z;
    int m0 = blockIdx.y * 64, n0 = blockIdx.x * 128;
    int tid = threadIdx.x, lane = tid & 63, w = tid >> 6, lg = lane >> 4, li = lane & 15;
    int rowA = tid >> 2, colA = (tid & 3) * 32;  // 64 rows x 128 f32 -> 32 f32/thread
    int rowB = tid >> 1, colB = (tid & 1) * 64;  // 128 rows x 128 bf16 -> 64/thread
    const float* pA = pw + (size_t)(m0 + rowA) * NC + colA;
    const u16*   pB = xt + ((size_t)b * NS + n0 + rowB) * NC + colB;
    f32x4 acc[4][2] = {};
#pragma unroll
    for (int k0 = 0; k0 < NC; k0 += 128) {
        // issue all global loads first: latency overlaps prior iter's MFMA + barrier
        f32x4 a[8];
#pragma unroll
        for (int i = 0; i < 8; i++) a[i] = *(const f32x4*)(pA + k0 + i * 4);
        i32x4 tb[8];
#pragma unroll
        for (int i = 0; i < 8; i++) tb[i] = *(const i32x4*)(pB + k0 + i * 8);
        __syncthreads();  // prior iter's frag reads complete before overwrite
#pragma unroll
        for (int i = 0; i < 4; i++) {
            i32x4 wa;
            wa[0] = pack2(a[2 * i][0], a[2 * i][1]);
            wa[1] = pack2(a[2 * i][2], a[2 * i][3]);
            wa[2] = pack2(a[2 * i + 1][0], a[2 * i + 1][1]);
            wa[3] = pack2(a[2 * i + 1][2], a[2 * i + 1][3]);
            *(i32x4*)&Ws[rowA][colA + i * 8] = wa;
        }
#pragma unroll
        for (int i = 0; i < 8; i++)
            *(i32x4*)&Xs[rowB][colB + i * 8] = tb[i];
        __syncthreads();
#pragma unroll
        for (int kc = 0; kc < 4; kc++) {
            u16x8 af[4], bfr[2];
#pragma unroll
            for (int mf = 0; mf < 4; mf++)
                af[mf] = *(const u16x8*)&Ws[mf * 16 + li][kc * 32 + lg * 8];
#pragma unroll
            for (int nf = 0; nf < 2; nf++)
                bfr[nf] = *(const u16x8*)&Xs[w * 32 + nf * 16 + li][kc * 32 + lg * 8];
#pragma unroll
            for (int mf = 0; mf < 4; mf++)
#pragma unroll
                for (int nf = 0; nf < 2; nf++)
                    acc[mf][nf] = MFMA(af[mf], bfr[nf], acc[mf][nf]);
        }
    }
    int sel = (m0 >> 6) % 3;   // 0=q, 1=k, 2=v (block-uniform)
    int n = m0 / 192;
    size_t bn = (size_t)b * NHEAD + n;
    if (sel == 0) {
#pragma unroll
        for (int mf = 0; mf < 4; mf++)
#pragma unroll
            for (int nf = 0; nf < 2; nf++) {
                int d0 = mf * 16 + lg * 4;
                int s = n0 + w * 32 + nf * 16 + li;
                u32x2 pk;
                pk[0] = pack2(acc[mf][nf][0] * QSCALE, acc[mf][nf][1] * QSCALE);
                pk[1] = pack2(acc[mf][nf][2] * QSCALE, acc[mf][nf][3] * QSCALE);
                *(u32x2*)(qb + (bn * NS + s) * HD + d0) = pk;
            }
    } else if (sel == 1) {
#pragma unroll
        for (int mf = 0; mf < 4; mf++)
#pragma unroll
            for (int nf = 0; nf < 2; nf++) {
                int d0 = mf * 16 + lg * 4;
                int s = n0 + w * 32 + nf * 16 + li;
                u32x2 pk;
                pk[0] = pack2(acc[mf][nf][0], acc[mf][nf][1]);
                pk[1] = pack2(acc[mf][nf][2], acc[mf][nf][3]);
                *(u32x2*)(kb + (bn * NS + s) * HD + d0) = pk;
            }
    } else {
#pragma unroll
        for (int mf = 0; mf < 4; mf++)
#pragma unroll
            for (int j = 0; j < 4; j++) {
                int r = mf * 16 + lg * 4 + j;
#pragma unroll
                for (int nf = 0; nf < 2; nf++) {
                    int s = n0 + w * 32 + nf * 16 + li;
                    vb[(bn * HD + r) * NS + s] = f2b(acc[mf][nf][j]);
                }
            }
    }
}

// ---------------- kernel 3: attention (128q blocks, Q-in-reg, in-register PV) ----------------
// Grid x: bit0 = t-half, rest = 128-row q tile. 4 waves = (tq q-half) x (tt t-half);
// each wave owns 64q x 32t. A 32-t slice = one complete softmax group.
// QK^T D-layout quad (t = lg*4+j) == 16x16x16 MFMA A-frag layout (k = lg*4+j),
// so normalized P feeds PV directly from registers: NO P LDS round-trip.
#define SMEM_K 0
#define SMEM_V 9216
#if __has_builtin(__builtin_amdgcn_mfma_f32_16x16x16bf16_1k)
#define PV16 1
#define SMEM_BYTES 34816
#else
#define PV16 0
#define SMEM_P 18432
#define SMEM_BYTES 38912
#endif
__global__ __launch_bounds__(256) void attn_k(const u16* __restrict__ qbuf, const u16* __restrict__ kbuf,
                                              const u16* __restrict__ vbuf, u16* __restrict__ ao0,
                                              u16* __restrict__ ao1) {
    __shared__ __attribute__((aligned(16))) char smem[SMEM_BYTES];
    u16 (*Ks)[72] = (u16(*)[72])(smem + SMEM_K);
    u16 (*Vs)[72] = (u16(*)[72])(smem + SMEM_V);
#if !PV16
    u16 (*Ps)[64][40] = (u16(*)[64][40])(smem + SMEM_P);  // [wave][q][t_local]
#endif
    float (*red)[68] = (float(*)[68])smem;  // 128*68*4 = 34816, aliases dead staging
    int b = blockIdx.z, n = blockIdx.y;
    int s0 = (blockIdx.x >> 1) * 128;
    int th = blockIdx.x & 1;
    u16* aoh = th ? ao1 : ao0;
    size_t bn = (size_t)b * NHEAD + n;
    const u16* qg = qbuf + (bn * NS + s0) * HD;
    const u16* kg = kbuf + (bn * NS + th * 512) * HD;
    const u16* vg = vbuf + bn * HD * NS + th * 512;
    int tid = threadIdx.x, lane = tid & 63, w = tid >> 6, lg = lane >> 4, li = lane & 15;
    int tq = w & 1, tt = w >> 1;  // wave's q-half (64 q), t-half (32 t) of the tile
    int srow = tid >> 2, sc8 = (tid & 3) * 16;  // 64 rows x 64 cols staging
    // prefetch tile 0 K/V into registers (T14 async-stage)
    i32x4 rk0 = *(const i32x4*)(kg + srow * HD + sc8);
    i32x4 rk1 = *(const i32x4*)(kg + srow * HD + sc8 + 8);
    i32x4 rv0 = *(const i32x4*)(vg + srow * NS + sc8);
    i32x4 rv1 = *(const i32x4*)(vg + srow * NS + sc8 + 8);
    // Q fragments: direct global->reg, once (B-operand: n=q=li, k=d=kc*32+lg*8+j)
    u16x8 bq[4][2];
#pragma unroll
    for (int qf = 0; qf < 4; qf++)
#pragma unroll
        for (int kc = 0; kc < 2; kc++)
            bq[qf][kc] = *(const u16x8*)(qg + (tq * 64 + qf * 16 + li) * HD + kc * 32 + lg * 8);
    f32x4 oacc[4][4] = {};
    for (int t0 = 0; t0 < 512; t0 += 64) {
        __syncthreads();  // prior tile's reads done before overwrite
        *(i32x4*)&Ks[srow][sc8]     = rk0;
        *(i32x4*)&Ks[srow][sc8 + 8] = rk1;
        *(i32x4*)&Vs[srow][sc8]     = rv0;
        *(i32x4*)&Vs[srow][sc8 + 8] = rv1;
        __syncthreads();
        if (t0 + 64 < 512) {  // issue next tile's loads; consumed at next loop top
            rk0 = *(const i32x4*)(kg + (t0 + 64 + srow) * HD + sc8);
            rk1 = *(const i32x4*)(kg + (t0 + 64 + srow) * HD + sc8 + 8);
            rv0 = *(const i32x4*)(vg + srow * NS + t0 + 64 + sc8);
            rv1 = *(const i32x4*)(vg + srow * NS + t0 + 64 + sc8 + 8);
        }
        // S^T: t = tt*32 + tf*16 + lg*4 + j, q = tq*64 + qf*16 + li
        u16x8 ak[2][2];
#pragma unroll
        for (int tf = 0; tf < 2; tf++)
#pragma unroll
            for (int kc = 0; kc < 2; kc++)
                ak[tf][kc] = *(const u16x8*)&Ks[tt * 32 + tf * 16 + li][kc * 32 + lg * 8];
        f32x4 sacc[2][4];
        __builtin_amdgcn_s_setprio(1);
#pragma unroll
        for (int tf = 0; tf < 2; tf++)
#pragma unroll
            for (int qf = 0; qf < 4; qf++) {
                f32x4 z = {0.f, 0.f, 0.f, 0.f};
                z = MFMA(ak[tf][0], bq[qf][0], z);
                sacc[tf][qf] = MFMA(ak[tf][1], bq[qf][1], z);
            }
        __builtin_amdgcn_s_setprio(0);
        // softmax (no max-shift; |S| tiny): per qf, wave's 32-t slice = 1 group
        u32x2 pp[4][2];
#pragma unroll
        for (int qf = 0; qf < 4; qf++) {
            float p[8];
            float sum = 0.f;
#pragma unroll
            for (int j = 0; j < 4; j++) { p[j] = exp2f(sacc[0][qf][j]); sum += p[j]; }
#pragma unroll
            for (int j = 0; j < 4; j++) { p[4 + j] = exp2f(sacc[1][qf][j]); sum += p[4 + j]; }
            sum += __shfl_xor(sum, 16);
            sum += __shfl_xor(sum, 32);
            float inv = 1.0f / sum;
#pragma unroll
            for (int tf = 0; tf < 2; tf++) {
                u32x2 pk;
                pk[0] = pack2(p[tf * 4 + 0] * inv, p[tf * 4 + 1] * inv);
                pk[1] = pack2(p[tf * 4 + 2] * inv, p[tf * 4 + 3] * inv);
                pp[qf][tf] = pk;
            }
        }
#if PV16
        // PV with 16x16x16: A = pp[qf][tf] (k = lg*4+j matches QK^T D quad),
        // B = V[d=li][t16 = lg*4+j] -> 8B ds_read_b64 per (nf,tf)
        s16x4 bv16[4][2];
#pragma unroll
        for (int nf = 0; nf < 4; nf++)
#pragma unroll
            for (int tf = 0; tf < 2; tf++)
                bv16[nf][tf] = *(const s16x4*)&Vs[nf * 16 + li][tt * 32 + tf * 16 + lg * 4];
        __builtin_amdgcn_s_setprio(1);
#pragma unroll
        for (int qf = 0; qf < 4; qf++) {
            s16x4 pa0 = __builtin_bit_cast(s16x4, pp[qf][0]);
            s16x4 pa1 = __builtin_bit_cast(s16x4, pp[qf][1]);
#pragma unroll
            for (int nf = 0; nf < 4; nf++) {
                oacc[qf][nf] = __builtin_amdgcn_mfma_f32_16x16x16bf16_1k(pa0, bv16[nf][0], oacc[qf][nf], 0, 0, 0);
                oacc[qf][nf] = __builtin_amdgcn_mfma_f32_16x16x16bf16_1k(pa1, bv16[nf][1], oacc[qf][nf], 0, 0, 0);
            }
        }
        __builtin_amdgcn_s_setprio(0);
#else
        // fallback: P via LDS round-trip (R7 path)
#pragma unroll
        for (int qf = 0; qf < 4; qf++)
#pragma unroll
            for (int tf = 0; tf < 2; tf++)
                *(u32x2*)&Ps[w][qf * 16 + li][tf * 16 + lg * 4] = pp[qf][tf];
        u16x8 pa[4];
#pragma unroll
        for (int qf = 0; qf < 4; qf++)
            pa[qf] = *(const u16x8*)&Ps[w][qf * 16 + li][lg * 8];
        u16x8 bv[4];
#pragma unroll
        for (int nf = 0; nf < 4; nf++)
            bv[nf] = *(const u16x8*)&Vs[nf * 16 + li][tt * 32 + lg * 8];
        __builtin_amdgcn_s_setprio(1);
#pragma unroll
        for (int qf = 0; qf < 4; qf++)
#pragma unroll
            for (int nf = 0; nf < 4; nf++)
                oacc[qf][nf] = MFMA(pa[qf], bv[nf], oacc[qf][nf]);
        __builtin_amdgcn_s_setprio(0);
#endif
    }
    // cross-wave t-half reduction: tt=1 partials -> LDS -> tt=0 adds & writes
    __syncthreads();  // all waves done with Ks/Vs reads; safe to alias
    if (tt == 1) {
#pragma unroll
        for (int qf = 0; qf < 4; qf++)
#pragma unroll
            for (int nf = 0; nf < 4; nf++)
#pragma unroll
                for (int j = 0; j < 4; j++)
                    red[tq * 64 + qf * 16 + lg * 4 + j][nf * 16 + li] = oacc[qf][nf][j];
    }
    __syncthreads();
    if (tt == 0) {
#pragma unroll
        for (int qf = 0; qf < 4; qf++)
#pragma unroll
            for (int nf = 0; nf < 4; nf++)
#pragma unroll
                for (int j = 0; j < 4; j++) {
                    int s = s0 + tq * 64 + qf * 16 + lg * 4 + j;
                    int c = n * HD + nf * 16 + li;
                    float v = oacc[qf][nf][j] + red[tq * 64 + qf * 16 + lg * 4 + j][nf * 16 + li];
                    aoh[((size_t)b * NS + s) * NC + c] = f2b(v);
                }
    }
}

// ------- kernel 4: out GEMM (K=512 concat of ao0/ao1) + bias + residual -------
// Tile 64x128, 4 waves, K-step 128 (4 iters, 8 barriers). out = [W,W] @ [O0;O1].
__global__ __launch_bounds__(256) void out_gemm(const float* __restrict__ ow, const u16* __restrict__ ao0,
                                                const u16* __restrict__ ao1,
                                                const float* __restrict__ outb, const float* __restrict__ in,
                                                float* __restrict__ out) {
    __shared__ __attribute__((aligned(16))) u16 Ws[64][136];
    __shared__ __attribute__((aligned(16))) u16 Xs[128][136];
    int b = blockIdx.z;
    int m0 = blockIdx.y * 64, n0 = blockIdx.x * 128;
    int tid = threadIdx.x, lane = tid & 63, w = tid >> 6, lg = lane >> 4, li = lane & 15;
    int rowA = tid >> 2, colA = (tid & 3) * 32;
    int rowB = tid >> 1, colB = (tid & 1) * 64;
    const float* pA = ow + (size_t)(m0 + rowA) * NC;
    size_t boff = ((size_t)b * NS + n0 + rowB) * NC + colB;
    f32x4 acc[4][2] = {};
#pragma unroll
    for (int k0 = 0; k0 < 2 * NC; k0 += 128) {
        const u16* pB = (k0 < NC ? ao0 : ao1) + boff + (k0 & (NC - 1));
        int ka = (k0 & (NC - 1)) + colA;
        // issue all global loads first: latency overlaps prior iter's MFMA + barrier
        f32x4 a[8];
#pragma unroll
        for (int i = 0; i < 8; i++) a[i] = *(const f32x4*)(pA + ka + i * 4);
        i32x4 tb[8];
#pragma unroll
        for (int i = 0; i < 8; i++) tb[i] = *(const i32x4*)(pB + i * 8);
        __syncthreads();  // prior iter's frag reads complete before overwrite
#pragma unroll
        for (int i = 0; i < 4; i++) {
            i32x4 wa;
            wa[0] = pack2(a[2 * i][0], a[2 * i][1]);
            wa[1] = pack2(a[2 * i][2], a[2 * i][3]);
            wa[2] = pack2(a[2 * i + 1][0], a[2 * i + 1][1]);
            wa[3] = pack2(a[2 * i + 1][2], a[2 * i + 1][3]);
            *(i32x4*)&Ws[rowA][colA + i * 8] = wa;
        }
#pragma unroll
        for (int i = 0; i < 8; i++)
            *(i32x4*)&Xs[rowB][colB + i * 8] = tb[i];
        __syncthreads();
#pragma unroll
        for (int kc = 0; kc < 4; kc++) {
            u16x8 af[4], bfr[2];
#pragma unroll
            for (int mf = 0; mf < 4; mf++)
                af[mf] = *(const u16x8*)&Ws[mf * 16 + li][kc * 32 + lg * 8];
#pragma unroll
            for (int nf = 0; nf < 2; nf++)
                bfr[nf] = *(const u16x8*)&Xs[w * 32 + nf * 16 + li][kc * 32 + lg * 8];
#pragma unroll
            for (int mf = 0; mf < 4; mf++)
#pragma unroll
                for (int nf = 0; nf < 2; nf++)
                    acc[mf][nf] = MFMA(af[mf], bfr[nf], acc[mf][nf]);
        }
    }
#pragma unroll
    for (int mf = 0; mf < 4; mf++)
#pragma unroll
        for (int j = 0; j < 4; j++) {
            int o = m0 + mf * 16 + lg * 4 + j;
            float bias = outb[o];
#pragma unroll
            for (int nf = 0; nf < 2; nf++) {
                int s = n0 + w * 32 + nf * 16 + li;
                size_t idx = ((size_t)b * NC + o) * NS + s;
                out[idx] = acc[mf][nf][j] + bias + in[idx];
            }
        }
}

extern "C" void kernel_launch(void* const* d_in, const int* in_sizes, int n_in,
                              void* d_out, int out_size, void* d_ws, size_t ws_size,
                              hipStream_t stream) {
    const float* input = (const float*)d_in[0];
    const float* gma = (const float*)d_in[1];
    const float* bta = (const float*)d_in[2];
    const float* mu  = (const float*)d_in[3];
    const float* var = (const float*)d_in[4];
    const float* dw  = (const float*)d_in[5];
    const float* pw  = (const float*)d_in[6];
    const float* ow  = (const float*)d_in[7];
    const float* ob  = (const float*)d_in[8];
    float* out = (float*)d_out;
    char* ws = (char*)d_ws;

    const size_t SZ_BIG = (size_t)NB * NS * NC * 2;      // 4 MiB each
    u16* xt  = (u16*)(ws);
    u16* qb  = (u16*)(ws + SZ_BIG);
    u16* kb  = (u16*)(ws + 2 * SZ_BIG);
    u16* vb  = (u16*)(ws + 3 * SZ_BIG);
    u16* ao1 = (u16*)(ws + 4 * SZ_BIG);
    u16* ao0 = xt;  // xt is dead after qkv_gemm; reuse for attention output

    xform<<<dim3(32, 8, 8), 256, 0, stream>>>(input, gma, bta, mu, var, dw, xt);
    qkv_gemm<<<dim3(8, 12, 8), 256, 0, stream>>>(pw, xt, qb, kb, vb);
    attn_k<<<dim3(16, 4, 8), 256, 0, stream>>>(qb, kb, vb, ao0, ao1);
    out_gemm<<<dim3(8, 4, 8), 256, 0, stream>>>(ow, ao0, ao1, ob, input, out);
}

// Round 14
// 58.435 us; speedup vs baseline: 1.1235x; 1.1235x over previous
//
#include <hip/hip_runtime.h>

#define NB 8
#define NC 256
#define NS 1024
#define NHEAD 4
#define HD 64
#define OC 768

// 0.125 (1/sqrt(HD)) * log2(e), folded into Q at qkv-write time
#define QSCALE 0.1803368801111204f

typedef float f32x4 __attribute__((ext_vector_type(4)));
typedef __bf16 bf16x8 __attribute__((ext_vector_type(8)));
typedef unsigned short u16;
typedef unsigned int u32;
typedef u16 u16x8 __attribute__((ext_vector_type(8)));
typedef u32 u32x2 __attribute__((ext_vector_type(2)));
typedef u32 u32x4 __attribute__((ext_vector_type(4)));
typedef int i32x4 __attribute__((ext_vector_type(4)));
typedef short s16x4 __attribute__((ext_vector_type(4)));

__device__ __forceinline__ u16 f2b(float f) {
    return __builtin_bit_cast(u16, (__bf16)f);  // hardware v_cvt (RNE)
}
__device__ __forceinline__ u32 pack2(float lo, float hi) {
    return (u32)f2b(lo) | ((u32)f2b(hi) << 16);  // fuses to v_cvt_pk_bf16_f32
}

__device__ __forceinline__ f32x4 MFMA(u16x8 a, u16x8 b, f32x4 c) {
    return __builtin_amdgcn_mfma_f32_16x16x32_bf16(
        __builtin_bit_cast(bf16x8, a), __builtin_bit_cast(bf16x8, b), c, 0, 0, 0);
}

// ------- kernel 1: BN-affine + transpose: in[b][c][s] f32 -> xt[b][s][c] bf16 -------
__global__ void xform(const float* __restrict__ in,
                      const float* __restrict__ gma, const float* __restrict__ bta,
                      const float* __restrict__ mu,  const float* __restrict__ var,
                      const float* __restrict__ dw,  u16* __restrict__ xt) {
    __shared__ float tile[32][33];
    __shared__ float ssc[32], ssh[32];
    int b = blockIdx.z, c0 = blockIdx.y * 32, s0 = blockIdx.x * 32;
    int tx = threadIdx.x & 31, ty = threadIdx.x >> 5;  // ty: 0..7
    if (threadIdx.x < 32) {
        int c = c0 + threadIdx.x;
        float sc = gma[c] * rsqrtf(var[c] + 1e-5f) * dw[c];
        ssc[threadIdx.x] = sc;
        ssh[threadIdx.x] = bta[c] * dw[c] - mu[c] * sc;
    }
    __syncthreads();
#pragma unroll
    for (int r = 0; r < 4; r++) {
        int c = ty + r * 8;
        tile[c][tx] = in[((size_t)b * NC + c0 + c) * NS + s0 + tx] * ssc[c] + ssh[c];
    }
    __syncthreads();
#pragma unroll
    for (int r = 0; r < 4; r++) {
        int s = ty + r * 8;
        xt[((size_t)b * NS + s0 + s) * NC + c0 + tx] = f2b(tile[tx][s]);
    }
}

// ---------------- kernel 2: QKV GEMM (768x1024x256 per batch) ----------------
// Tile 64x128, 4 waves (each 64x32), K-step 64. A staged from f32 pw inline.
// Global loads issued BEFORE the barrier (latency overlaps prior MFMA tail).
// Each 64-row m-tile is purely q, k, or v: sel=(m0/64)%3, block-uniform.
__global__ __launch_bounds__(256) void qkv_gemm(const float* __restrict__ pw, const u16* __restrict__ xt,
                                                u16* __restrict__ qb, u16* __restrict__ kb,
                                                u16* __restrict__ vb) {
    __shared__ __attribute__((aligned(16))) u16 Ws[64][72];
    __shared__ __attribute__((aligned(16))) u16 Xs[128][72];
    int b = blockIdx.z;
    int m0 = blockIdx.y * 64, n0 = blockIdx.x * 128;
    int tid = threadIdx.x, lane = tid & 63, w = tid >> 6, lg = lane >> 4, li = lane & 15;
    int rowA = tid >> 2, colA = (tid & 3) * 16;  // 64 rows x 64 f32 -> 16 f32/thread
    int rowB = tid >> 1, colB = (tid & 1) * 32;  // 128 rows x 64 bf16 -> 32/thread
    const float* pA = pw + (size_t)(m0 + rowA) * NC + colA;
    const u16*   pB = xt + ((size_t)b * NS + n0 + rowB) * NC + colB;
    f32x4 acc[4][2] = {};
#pragma unroll
    for (int k0 = 0; k0 < NC; k0 += 64) {
        // issue global loads first: latency overlaps prior iter's MFMA + barrier
        f32x4 a0 = *(const f32x4*)(pA + k0);
        f32x4 a1 = *(const f32x4*)(pA + k0 + 4);
        f32x4 a2 = *(const f32x4*)(pA + k0 + 8);
        f32x4 a3 = *(const f32x4*)(pA + k0 + 12);
        i32x4 tb0 = *(const i32x4*)(pB + k0);
        i32x4 tb1 = *(const i32x4*)(pB + k0 + 8);
        i32x4 tb2 = *(const i32x4*)(pB + k0 + 16);
        i32x4 tb3 = *(const i32x4*)(pB + k0 + 24);
        __syncthreads();  // prior iter's frag reads complete before overwrite
        i32x4 wa0, wa1;
        wa0[0] = pack2(a0[0], a0[1]); wa0[1] = pack2(a0[2], a0[3]);
        wa0[2] = pack2(a1[0], a1[1]); wa0[3] = pack2(a1[2], a1[3]);
        wa1[0] = pack2(a2[0], a2[1]); wa1[1] = pack2(a2[2], a2[3]);
        wa1[2] = pack2(a3[0], a3[1]); wa1[3] = pack2(a3[2], a3[3]);
        *(i32x4*)&Ws[rowA][colA]     = wa0;
        *(i32x4*)&Ws[rowA][colA + 8] = wa1;
        *(i32x4*)&Xs[rowB][colB]      = tb0;
        *(i32x4*)&Xs[rowB][colB + 8]  = tb1;
        *(i32x4*)&Xs[rowB][colB + 16] = tb2;
        *(i32x4*)&Xs[rowB][colB + 24] = tb3;
        __syncthreads();
        u16x8 af[4][2], bfr[2][2];
#pragma unroll
        for (int mf = 0; mf < 4; mf++)
#pragma unroll
            for (int kc = 0; kc < 2; kc++)
                af[mf][kc] = *(const u16x8*)&Ws[mf * 16 + li][kc * 32 + lg * 8];
#pragma unroll
        for (int nf = 0; nf < 2; nf++)
#pragma unroll
            for (int kc = 0; kc < 2; kc++)
                bfr[nf][kc] = *(const u16x8*)&Xs[w * 32 + nf * 16 + li][kc * 32 + lg * 8];
#pragma unroll
        for (int kc = 0; kc < 2; kc++)
#pragma unroll
            for (int mf = 0; mf < 4; mf++)
#pragma unroll
                for (int nf = 0; nf < 2; nf++)
                    acc[mf][nf] = MFMA(af[mf][kc], bfr[nf][kc], acc[mf][nf]);
    }
    int sel = (m0 >> 6) % 3;   // 0=q, 1=k, 2=v (block-uniform)
    int n = m0 / 192;
    size_t bn = (size_t)b * NHEAD + n;
    if (sel == 0) {
#pragma unroll
        for (int mf = 0; mf < 4; mf++)
#pragma unroll
            for (int nf = 0; nf < 2; nf++) {
                int d0 = mf * 16 + lg * 4;
                int s = n0 + w * 32 + nf * 16 + li;
                u32x2 pk;
                pk[0] = pack2(acc[mf][nf][0] * QSCALE, acc[mf][nf][1] * QSCALE);
                pk[1] = pack2(acc[mf][nf][2] * QSCALE, acc[mf][nf][3] * QSCALE);
                *(u32x2*)(qb + (bn * NS + s) * HD + d0) = pk;
            }
    } else if (sel == 1) {
#pragma unroll
        for (int mf = 0; mf < 4; mf++)
#pragma unroll
            for (int nf = 0; nf < 2; nf++) {
                int d0 = mf * 16 + lg * 4;
                int s = n0 + w * 32 + nf * 16 + li;
                u32x2 pk;
                pk[0] = pack2(acc[mf][nf][0], acc[mf][nf][1]);
                pk[1] = pack2(acc[mf][nf][2], acc[mf][nf][3]);
                *(u32x2*)(kb + (bn * NS + s) * HD + d0) = pk;
            }
    } else {
#pragma unroll
        for (int mf = 0; mf < 4; mf++)
#pragma unroll
            for (int j = 0; j < 4; j++) {
                int r = mf * 16 + lg * 4 + j;
#pragma unroll
                for (int nf = 0; nf < 2; nf++) {
                    int s = n0 + w * 32 + nf * 16 + li;
                    vb[(bn * HD + r) * NS + s] = f2b(acc[mf][nf][j]);
                }
            }
    }
}

// ---------------- kernel 3: attention (128q blocks, Q-in-reg, in-register PV) ----------------
// Grid x: bit0 = t-half, rest = 128-row q tile. 4 waves = (tq q-half) x (tt t-half);
// each wave owns 64q x 32t. A 32-t slice = one complete softmax group.
// QK^T D-layout quad (t = lg*4+j) == 16x16x16 MFMA A-frag layout (k = lg*4+j),
// so normalized P feeds PV directly from registers: NO P LDS round-trip.
#define SMEM_K 0
#define SMEM_V 9216
#if __has_builtin(__builtin_amdgcn_mfma_f32_16x16x16bf16_1k)
#define PV16 1
#define SMEM_BYTES 34816
#else
#define PV16 0
#define SMEM_P 18432
#define SMEM_BYTES 38912
#endif
__global__ __launch_bounds__(256) void attn_k(const u16* __restrict__ qbuf, const u16* __restrict__ kbuf,
                                              const u16* __restrict__ vbuf, u16* __restrict__ ao0,
                                              u16* __restrict__ ao1) {
    __shared__ __attribute__((aligned(16))) char smem[SMEM_BYTES];
    u16 (*Ks)[72] = (u16(*)[72])(smem + SMEM_K);
    u16 (*Vs)[72] = (u16(*)[72])(smem + SMEM_V);
#if !PV16
    u16 (*Ps)[64][40] = (u16(*)[64][40])(smem + SMEM_P);  // [wave][q][t_local]
#endif
    float (*red)[68] = (float(*)[68])smem;  // 128*68*4 = 34816, aliases dead staging
    int b = blockIdx.z, n = blockIdx.y;
    int s0 = (blockIdx.x >> 1) * 128;
    int th = blockIdx.x & 1;
    u16* aoh = th ? ao1 : ao0;
    size_t bn = (size_t)b * NHEAD + n;
    const u16* qg = qbuf + (bn * NS + s0) * HD;
    const u16* kg = kbuf + (bn * NS + th * 512) * HD;
    const u16* vg = vbuf + bn * HD * NS + th * 512;
    int tid = threadIdx.x, lane = tid & 63, w = tid >> 6, lg = lane >> 4, li = lane & 15;
    int tq = w & 1, tt = w >> 1;  // wave's q-half (64 q), t-half (32 t) of the tile
    int srow = tid >> 2, sc8 = (tid & 3) * 16;  // 64 rows x 64 cols staging
    // prefetch tile 0 K/V into registers (T14 async-stage)
    i32x4 rk0 = *(const i32x4*)(kg + srow * HD + sc8);
    i32x4 rk1 = *(const i32x4*)(kg + srow * HD + sc8 + 8);
    i32x4 rv0 = *(const i32x4*)(vg + srow * NS + sc8);
    i32x4 rv1 = *(const i32x4*)(vg + srow * NS + sc8 + 8);
    // Q fragments: direct global->reg, once (B-operand: n=q=li, k=d=kc*32+lg*8+j)
    u16x8 bq[4][2];
#pragma unroll
    for (int qf = 0; qf < 4; qf++)
#pragma unroll
        for (int kc = 0; kc < 2; kc++)
            bq[qf][kc] = *(const u16x8*)(qg + (tq * 64 + qf * 16 + li) * HD + kc * 32 + lg * 8);
    f32x4 oacc[4][4] = {};
    for (int t0 = 0; t0 < 512; t0 += 64) {
        __syncthreads();  // prior tile's reads done before overwrite
        *(i32x4*)&Ks[srow][sc8]     = rk0;
        *(i32x4*)&Ks[srow][sc8 + 8] = rk1;
        *(i32x4*)&Vs[srow][sc8]     = rv0;
        *(i32x4*)&Vs[srow][sc8 + 8] = rv1;
        __syncthreads();
        if (t0 + 64 < 512) {  // issue next tile's loads; consumed at next loop top
            rk0 = *(const i32x4*)(kg + (t0 + 64 + srow) * HD + sc8);
            rk1 = *(const i32x4*)(kg + (t0 + 64 + srow) * HD + sc8 + 8);
            rv0 = *(const i32x4*)(vg + srow * NS + t0 + 64 + sc8);
            rv1 = *(const i32x4*)(vg + srow * NS + t0 + 64 + sc8 + 8);
        }
        // S^T: t = tt*32 + tf*16 + lg*4 + j, q = tq*64 + qf*16 + li
        u16x8 ak[2][2];
#pragma unroll
        for (int tf = 0; tf < 2; tf++)
#pragma unroll
            for (int kc = 0; kc < 2; kc++)
                ak[tf][kc] = *(const u16x8*)&Ks[tt * 32 + tf * 16 + li][kc * 32 + lg * 8];
        f32x4 sacc[2][4];
        __builtin_amdgcn_s_setprio(1);
#pragma unroll
        for (int tf = 0; tf < 2; tf++)
#pragma unroll
            for (int qf = 0; qf < 4; qf++) {
                f32x4 z = {0.f, 0.f, 0.f, 0.f};
                z = MFMA(ak[tf][0], bq[qf][0], z);
                sacc[tf][qf] = MFMA(ak[tf][1], bq[qf][1], z);
            }
        __builtin_amdgcn_s_setprio(0);
        // softmax (no max-shift; |S| tiny): per qf, wave's 32-t slice = 1 group
        u32x2 pp[4][2];
#pragma unroll
        for (int qf = 0; qf < 4; qf++) {
            float p[8];
            float sum = 0.f;
#pragma unroll
            for (int j = 0; j < 4; j++) { p[j] = exp2f(sacc[0][qf][j]); sum += p[j]; }
#pragma unroll
            for (int j = 0; j < 4; j++) { p[4 + j] = exp2f(sacc[1][qf][j]); sum += p[4 + j]; }
            sum += __shfl_xor(sum, 16);
            sum += __shfl_xor(sum, 32);
            float inv = 1.0f / sum;
#pragma unroll
            for (int tf = 0; tf < 2; tf++) {
                u32x2 pk;
                pk[0] = pack2(p[tf * 4 + 0] * inv, p[tf * 4 + 1] * inv);
                pk[1] = pack2(p[tf * 4 + 2] * inv, p[tf * 4 + 3] * inv);
                pp[qf][tf] = pk;
            }
        }
#if PV16
        // PV with 16x16x16: A = pp[qf][tf] (k = lg*4+j matches QK^T D quad),
        // B = V[d=li][t16 = lg*4+j] -> 8B ds_read_b64 per (nf,tf)
        s16x4 bv16[4][2];
#pragma unroll
        for (int nf = 0; nf < 4; nf++)
#pragma unroll
            for (int tf = 0; tf < 2; tf++)
                bv16[nf][tf] = *(const s16x4*)&Vs[nf * 16 + li][tt * 32 + tf * 16 + lg * 4];
        __builtin_amdgcn_s_setprio(1);
#pragma unroll
        for (int qf = 0; qf < 4; qf++) {
            s16x4 pa0 = __builtin_bit_cast(s16x4, pp[qf][0]);
            s16x4 pa1 = __builtin_bit_cast(s16x4, pp[qf][1]);
#pragma unroll
            for (int nf = 0; nf < 4; nf++) {
                oacc[qf][nf] = __builtin_amdgcn_mfma_f32_16x16x16bf16_1k(pa0, bv16[nf][0], oacc[qf][nf], 0, 0, 0);
                oacc[qf][nf] = __builtin_amdgcn_mfma_f32_16x16x16bf16_1k(pa1, bv16[nf][1], oacc[qf][nf], 0, 0, 0);
            }
        }
        __builtin_amdgcn_s_setprio(0);
#else
        // fallback: P via LDS round-trip (R7 path)
#pragma unroll
        for (int qf = 0; qf < 4; qf++)
#pragma unroll
            for (int tf = 0; tf < 2; tf++)
                *(u32x2*)&Ps[w][qf * 16 + li][tf * 16 + lg * 4] = pp[qf][tf];
        u16x8 pa[4];
#pragma unroll
        for (int qf = 0; qf < 4; qf++)
            pa[qf] = *(const u16x8*)&Ps[w][qf * 16 + li][lg * 8];
        u16x8 bv[4];
#pragma unroll
        for (int nf = 0; nf < 4; nf++)
            bv[nf] = *(const u16x8*)&Vs[nf * 16 + li][tt * 32 + lg * 8];
        __builtin_amdgcn_s_setprio(1);
#pragma unroll
        for (int qf = 0; qf < 4; qf++)
#pragma unroll
            for (int nf = 0; nf < 4; nf++)
                oacc[qf][nf] = MFMA(pa[qf], bv[nf], oacc[qf][nf]);
        __builtin_amdgcn_s_setprio(0);
#endif
    }
    // cross-wave t-half reduction: tt=1 partials -> LDS -> tt=0 adds & writes
    __syncthreads();  // all waves done with Ks/Vs reads; safe to alias
    if (tt == 1) {
#pragma unroll
        for (int qf = 0; qf < 4; qf++)
#pragma unroll
            for (int nf = 0; nf < 4; nf++)
#pragma unroll
                for (int j = 0; j < 4; j++)
                    red[tq * 64 + qf * 16 + lg * 4 + j][nf * 16 + li] = oacc[qf][nf][j];
    }
    __syncthreads();
    if (tt == 0) {
#pragma unroll
        for (int qf = 0; qf < 4; qf++)
#pragma unroll
            for (int nf = 0; nf < 4; nf++)
#pragma unroll
                for (int j = 0; j < 4; j++) {
                    int s = s0 + tq * 64 + qf * 16 + lg * 4 + j;
                    int c = n * HD + nf * 16 + li;
                    float v = oacc[qf][nf][j] + red[tq * 64 + qf * 16 + lg * 4 + j][nf * 16 + li];
                    aoh[((size_t)b * NS + s) * NC + c] = f2b(v);
                }
    }
}

// ------- kernel 4: out GEMM (K=512 concat of ao0/ao1) + bias + residual -------
// Tile 64x128, 4 waves, K-step 64. out = out_w @ (O0 + O1) == [W,W] @ [O0;O1].
__global__ __launch_bounds__(256) void out_gemm(const float* __restrict__ ow, const u16* __restrict__ ao0,
                                                const u16* __restrict__ ao1,
                                                const float* __restrict__ outb, const float* __restrict__ in,
                                                float* __restrict__ out) {
    __shared__ __attribute__((aligned(16))) u16 Ws[64][72];
    __shared__ __attribute__((aligned(16))) u16 Xs[128][72];
    int b = blockIdx.z;
    int m0 = blockIdx.y * 64, n0 = blockIdx.x * 128;
    int tid = threadIdx.x, lane = tid & 63, w = tid >> 6, lg = lane >> 4, li = lane & 15;
    int rowA = tid >> 2, colA = (tid & 3) * 16;
    int rowB = tid >> 1, colB = (tid & 1) * 32;
    const float* pA = ow + (size_t)(m0 + rowA) * NC + colA;
    size_t boff = ((size_t)b * NS + n0 + rowB) * NC + colB;
    f32x4 acc[4][2] = {};
#pragma unroll
    for (int k0 = 0; k0 < 2 * NC; k0 += 64) {
        const u16* pB = (k0 < NC ? ao0 : ao1) + boff + (k0 & (NC - 1));
        int ka = k0 & (NC - 1);
        // issue global loads first: latency overlaps prior iter's MFMA + barrier
        f32x4 a0 = *(const f32x4*)(pA + ka);
        f32x4 a1 = *(const f32x4*)(pA + ka + 4);
        f32x4 a2 = *(const f32x4*)(pA + ka + 8);
        f32x4 a3 = *(const f32x4*)(pA + ka + 12);
        i32x4 tb0 = *(const i32x4*)(pB);
        i32x4 tb1 = *(const i32x4*)(pB + 8);
        i32x4 tb2 = *(const i32x4*)(pB + 16);
        i32x4 tb3 = *(const i32x4*)(pB + 24);
        __syncthreads();  // prior iter's frag reads complete before overwrite
        i32x4 wa0, wa1;
        wa0[0] = pack2(a0[0], a0[1]); wa0[1] = pack2(a0[2], a0[3]);
        wa0[2] = pack2(a1[0], a1[1]); wa0[3] = pack2(a1[2], a1[3]);
        wa1[0] = pack2(a2[0], a2[1]); wa1[1] = pack2(a2[2], a2[3]);
        wa1[2] = pack2(a3[0], a3[1]); wa1[3] = pack2(a3[2], a3[3]);
        *(i32x4*)&Ws[rowA][colA]     = wa0;
        *(i32x4*)&Ws[rowA][colA + 8] = wa1;
        *(i32x4*)&Xs[rowB][colB]      = tb0;
        *(i32x4*)&Xs[rowB][colB + 8]  = tb1;
        *(i32x4*)&Xs[rowB][colB + 16] = tb2;
        *(i32x4*)&Xs[rowB][colB + 24] = tb3;
        __syncthreads();
        u16x8 af[4][2], bfr[2][2];
#pragma unroll
        for (int mf = 0; mf < 4; mf++)
#pragma unroll
            for (int kc = 0; kc < 2; kc++)
                af[mf][kc] = *(const u16x8*)&Ws[mf * 16 + li][kc * 32 + lg * 8];
#pragma unroll
        for (int nf = 0; nf < 2; nf++)
#pragma unroll
            for (int kc = 0; kc < 2; kc++)
                bfr[nf][kc] = *(const u16x8*)&Xs[w * 32 + nf * 16 + li][kc * 32 + lg * 8];
#pragma unroll
        for (int kc = 0; kc < 2; kc++)
#pragma unroll
            for (int mf = 0; mf < 4; mf++)
#pragma unroll
                for (int nf = 0; nf < 2; nf++)
                    acc[mf][nf] = MFMA(af[mf][kc], bfr[nf][kc], acc[mf][nf]);
    }
#pragma unroll
    for (int mf = 0; mf < 4; mf++)
#pragma unroll
        for (int j = 0; j < 4; j++) {
            int o = m0 + mf * 16 + lg * 4 + j;
            float bias = outb[o];
#pragma unroll
            for (int nf = 0; nf < 2; nf++) {
                int s = n0 + w * 32 + nf * 16 + li;
                size_t idx = ((size_t)b * NC + o) * NS + s;
                out[idx] = acc[mf][nf][j] + bias + in[idx];
            }
        }
}

extern "C" void kernel_launch(void* const* d_in, const int* in_sizes, int n_in,
                              void* d_out, int out_size, void* d_ws, size_t ws_size,
                              hipStream_t stream) {
    const float* input = (const float*)d_in[0];
    const float* gma = (const float*)d_in[1];
    const float* bta = (const float*)d_in[2];
    const float* mu  = (const float*)d_in[3];
    const float* var = (const float*)d_in[4];
    const float* dw  = (const float*)d_in[5];
    const float* pw  = (const float*)d_in[6];
    const float* ow  = (const float*)d_in[7];
    const float* ob  = (const float*)d_in[8];
    float* out = (float*)d_out;
    char* ws = (char*)d_ws;

    const size_t SZ_BIG = (size_t)NB * NS * NC * 2;      // 4 MiB each
    u16* xt  = (u16*)(ws);
    u16* qb  = (u16*)(ws + SZ_BIG);
    u16* kb  = (u16*)(ws + 2 * SZ_BIG);
    u16* vb  = (u16*)(ws + 3 * SZ_BIG);
    u16* ao1 = (u16*)(ws + 4 * SZ_BIG);
    u16* ao0 = xt;  // xt is dead after qkv_gemm; reuse for attention output

    xform<<<dim3(32, 8, 8), 256, 0, stream>>>(input, gma, bta, mu, var, dw, xt);
    qkv_gemm<<<dim3(8, 12, 8), 256, 0, stream>>>(pw, xt, qb, kb, vb);
    attn_k<<<dim3(16, 4, 8), 256, 0, stream>>>(qb, kb, vb, ao0, ao1);
    out_gemm<<<dim3(8, 4, 8), 256, 0, stream>>>(ow, ao0, ao1, ob, input, out);
}